// Round 1
// baseline (1619.206 us; speedup 1.0000x reference)
//
#include <hip/hip_runtime.h>
#include <math.h>

#define NMAT 240
#define NFULL 256
#define NG (NMAT*NMAT)          // 57600
#define ITERS 30
#define ORD_SCALE (1.0f/61440.0f)

// Persistent device state (re-initialized every kernel_launch call; ~1.6 MB)
__device__ float g_Gl[NG], g_mG[NG], g_vG[NG];
__device__ float g_S[2][NG];       // ping-pong sigmoid(Gl)
__device__ float g_W[NG];          // (P - T) * P
__device__ float g_Bt[NG];         // Bt[k*240+w] = A[w*256 + 16 + k]
__device__ float g_tau[2][NFULL], g_mT[NFULL], g_vT[NFULL];
__device__ float g_acc[2];         // [0]=sum (P-T)^2, [1]=sum S*relu(diff)^2

__device__ __forceinline__ float sigm(float x) { return 1.0f / (1.0f + expf(-x)); }

__global__ void k_init(const float* __restrict__ A,
                       const float* __restrict__ Gl0,
                       const float* __restrict__ tau0)
{
    int idx = blockIdx.x * 256 + threadIdx.x;
    if (idx < NG) {
        float g = Gl0[idx];
        g_Gl[idx] = g;
        g_mG[idx] = 0.f; g_vG[idx] = 0.f;
        g_S[0][idx] = sigm(g);
        int k = idx / NMAT, w = idx - k * NMAT;
        g_Bt[idx] = A[w * NFULL + 16 + k];
    }
    if (idx < NFULL) {
        g_tau[0][idx] = tau0[idx];
        g_mT[idx] = 0.f; g_vT[idx] = 0.f;
    }
    if (idx < 2) g_acc[idx] = 0.f;
}

// W[u,w] = (P[u,w] - T[u,w]) * P[u,w],  P = prod_k (1 - 2*B[w,k]*S[u,k])
__global__ __launch_bounds__(256) void k_prod(int par)
{
    __shared__ float sl[NMAT];
    const int u = blockIdx.x, w = threadIdx.x;
    const float* __restrict__ S = g_S[par];
    if (w < NMAT) sl[w] = S[u * NMAT + w];
    __syncthreads();
    if (w >= NMAT) return;
    float p = 1.0f;
    for (int k = 0; k < NMAT; ++k) {
        float b = g_Bt[k * NMAT + w];     // coalesced across w
        float s = sl[k];
        float term = 1.0f - 2.0f * b * s;
        p *= term;
    }
    float t = (w == u) ? -1.0f : 1.0f;
    g_W[u * NMAT + w] = (p - t) * p;
}

// blocks 0..239: grad wrt Gl[u,:] + Adam + new sigmoid -> S[par^1]
// block 240:     grad wrt tau + Adam -> tau[par^1]
__global__ __launch_bounds__(256) void k_grad(const float* __restrict__ A,
                                              int par, float bc1, float bc2)
{
    const int tid = threadIdx.x;
    const float* __restrict__ S_in  = g_S[par];
    const float* __restrict__ tauin = g_tau[par];

    if (blockIdx.x == NMAT) {
        // ---- tau update ----
        __shared__ float tl[NFULL];
        tl[tid] = tauin[tid];
        __syncthreads();
        float colsum = 0.f;
        if (tid >= 16) {
            const int jj = tid - 16;
            for (int i = 0; i < NMAT; ++i) {
                float d = tl[i] - tl[tid] + 0.1f;
                float r = fmaxf(d, 0.f);
                colsum += S_in[i * NMAT + jj] * (2.0f * r);   // coalesced across tid
            }
        }
        float rowsum = 0.f;
        if (tid < NMAT) {
            for (int j = 16; j < NFULL; ++j) {
                float d = tl[tid] - tl[j] + 0.1f;
                float r = fmaxf(d, 0.f);
                rowsum += S_in[tid * NMAT + (j - 16)] * (2.0f * r);
            }
        }
        float g = (rowsum - colsum) * ORD_SCALE;
        float m = 0.9f * g_mT[tid] + 0.1f * g;
        float v = 0.999f * g_vT[tid] + 0.001f * g * g;
        g_mT[tid] = m; g_vT[tid] = v;
        float upd = 0.1f * (m / bc1) / (sqrtf(v / bc2) + 1e-8f);
        g_tau[par ^ 1][tid] = tauin[tid] - upd;
        return;
    }

    // ---- Gl update, row u ----
    const int u = blockIdx.x;
    __shared__ float wl[NMAT];
    if (tid < NMAT) wl[tid] = g_W[u * NMAT + tid];
    __syncthreads();
    if (tid >= NMAT) return;
    const int j = tid;
    const int idx = u * NMAT + j;
    const float s = S_in[idx];

    float acc = 0.f;
    for (int w = 0; w < NMAT; ++w) {
        float b = A[w * NFULL + 16 + j];          // coalesced across j
        float term = 1.0f - 2.0f * b * s;
        float ww = wl[w];                          // LDS broadcast
        // Guard exact-zero denominator (P would be 0 there -> contribution ~0)
        acc += (term != 0.0f) ? (ww * b / term) : 0.0f;
    }
    float g_odd = -acc * (1.0f / 240.0f);

    float d = tauin[u] - tauin[16 + j] + 0.1f;
    float r = fmaxf(d, 0.f);
    float g_ord = r * r * ORD_SCALE;

    float gS  = g_odd + g_ord;
    float gGl = gS * s * (1.0f - s);               // sigmoid'

    float m = 0.9f * g_mG[idx] + 0.1f * gGl;
    float v = 0.999f * g_vG[idx] + 0.001f * gGl * gGl;
    g_mG[idx] = m; g_vG[idx] = v;
    float p = g_Gl[idx] - 0.1f * (m / bc1) / (sqrtf(v / bc2) + 1e-8f);
    g_Gl[idx] = p;
    g_S[par ^ 1][idx] = sigm(p);
}

// Final loss partial sums: block u covers row u of both L_odd and L_order
__global__ __launch_bounds__(256) void k_final(int par)
{
    __shared__ float sl[NMAT];
    __shared__ float rodd[4], rord[4];
    const int u = blockIdx.x, tid = threadIdx.x;
    const float* __restrict__ S   = g_S[par];
    const float* __restrict__ tau = g_tau[par];
    if (tid < NMAT) sl[tid] = S[u * NMAT + tid];
    __syncthreads();

    float odd = 0.f, ord = 0.f;
    if (tid < NMAT) {
        float p = 1.0f;
        for (int k = 0; k < NMAT; ++k) {
            float b = g_Bt[k * NMAT + tid];
            float term = 1.0f - 2.0f * b * sl[k];
            p *= term;
        }
        float t = (tid == u) ? -1.0f : 1.0f;
        float r = p - t;
        odd = r * r;
        float d = tau[u] - tau[16 + tid] + 0.1f;
        float rr = fmaxf(d, 0.f);
        ord = sl[tid] * rr * rr;
    }
    // wave reduce (64 lanes) then cross-wave via LDS
    for (int off = 32; off > 0; off >>= 1) {
        odd += __shfl_down(odd, off);
        ord += __shfl_down(ord, off);
    }
    int lane = tid & 63, wv = tid >> 6;
    if (lane == 0) { rodd[wv] = odd; rord[wv] = ord; }
    __syncthreads();
    if (tid == 0) {
        float so = rodd[0] + rodd[1] + rodd[2] + rodd[3];
        float sr = rord[0] + rord[1] + rord[2] + rord[3];
        atomicAdd(&g_acc[0], so);
        atomicAdd(&g_acc[1], sr);
    }
}

__global__ void k_out(float* __restrict__ out)
{
    out[0] = g_acc[0] / 960.0f + g_acc[1] / 61440.0f;
}

extern "C" void kernel_launch(void* const* d_in, const int* in_sizes, int n_in,
                              void* d_out, int out_size, void* d_ws, size_t ws_size,
                              hipStream_t stream)
{
    const float* A    = (const float*)d_in[0];
    const float* Gl0  = (const float*)d_in[1];
    const float* tau0 = (const float*)d_in[2];
    float* out = (float*)d_out;

    k_init<<<(NG + 255) / 256, 256, 0, stream>>>(A, Gl0, tau0);

    for (int t = 0; t < ITERS; ++t) {
        int par = t & 1;
        k_prod<<<NMAT, 256, 0, stream>>>(par);
        double tt = (double)(t + 1);
        float bc1 = (float)(1.0 - pow((double)0.9f,   tt));
        float bc2 = (float)(1.0 - pow((double)0.999f, tt));
        k_grad<<<NMAT + 1, 256, 0, stream>>>(A, par, bc1, bc2);
    }
    // after 30 iterations final params live in parity 0
    k_final<<<NMAT, 256, 0, stream>>>(0);
    k_out<<<1, 1, 0, stream>>>(out);
}

// Round 2
// 515.415 us; speedup vs baseline: 3.1416x; 3.1416x over previous
//
#include <hip/hip_runtime.h>
#include <math.h>

#define NMAT 240
#define NFULL 256
#define NG (NMAT*NMAT)          // 57600
#define ITERS 30
#define ORD_SCALE (1.0f/61440.0f)
#define CHW 60                  // 240 / 4 chunks

// Persistent device state (re-initialized every kernel_launch call; ~1.6 MB)
__device__ float g_Gl[NG], g_mG[NG], g_vG[NG];
__device__ float g_S[2][NG];       // ping-pong sigmoid(Gl)
__device__ float g_Bt[NG];         // Bt[k*240+w] = A[w*256 + 16 + k]
__device__ float g_tau[2][NFULL], g_mT[NFULL], g_vT[NFULL];
__device__ float g_acc[2];         // [0]=sum (P-T)^2, [1]=sum S*relu(diff)^2

__device__ __forceinline__ float sigm(float x) { return 1.0f / (1.0f + expf(-x)); }

__global__ void k_init(const float* __restrict__ A,
                       const float* __restrict__ Gl0,
                       const float* __restrict__ tau0)
{
    int idx = blockIdx.x * 256 + threadIdx.x;
    if (idx < NG) {
        float g = Gl0[idx];
        g_Gl[idx] = g;
        g_mG[idx] = 0.f; g_vG[idx] = 0.f;
        g_S[0][idx] = sigm(g);
        int k = idx / NMAT, w = idx - k * NMAT;
        g_Bt[idx] = A[w * NFULL + 16 + k];
    }
    if (idx < NFULL) {
        g_tau[0][idx] = tau0[idx];
        g_mT[idx] = 0.f; g_vT[idx] = 0.f;
    }
    if (idx < 2) g_acc[idx] = 0.f;
}

// One full inner-opt iteration, fused.
// blocks 0..239 (row u): P[u,:] -> W[u,:] (LDS) -> dL/dGl[u,:] -> Adam -> S_out[u,:]
// block 240: tau grad + Adam -> tau_out
// 1024 threads = 4 chunks (c) x 256 lanes (j); the 240-deep loops are split 4x60.
__global__ __launch_bounds__(1024) void k_iter(const float* __restrict__ A,
                                               int par, float bc1, float bc2)
{
    const int tid = threadIdx.x;
    const int c = tid >> 8;          // chunk 0..3
    const int j = tid & 255;         // lane 0..255
    const float* __restrict__ S_in  = g_S[par];
    const float* __restrict__ tauin = g_tau[par];

    if (blockIdx.x == NMAT) {
        // ---- tau update ----
        __shared__ float tl[NFULL];
        __shared__ float cpart[4][NFULL];
        __shared__ float rpart[4][NFULL];
        if (tid < NFULL) tl[tid] = tauin[tid];
        __syncthreads();
        float colsum = 0.f, rowsum = 0.f;
        if (j >= 16) {
            const int jj = j - 16;
            #pragma unroll 4
            for (int i = c * CHW; i < c * CHW + CHW; ++i) {
                float d = tl[i] - tl[j] + 0.1f;
                float r = fmaxf(d, 0.f);
                colsum += S_in[i * NMAT + jj] * (2.0f * r);   // coalesced across j
            }
        }
        if (j < NMAT) {
            #pragma unroll 4
            for (int q = c * CHW; q < c * CHW + CHW; ++q) {
                float d = tl[j] - tl[16 + q] + 0.1f;
                float r = fmaxf(d, 0.f);
                rowsum += S_in[j * NMAT + q] * (2.0f * r);
            }
        }
        cpart[c][j] = colsum; rpart[c][j] = rowsum;
        __syncthreads();
        if (c == 0) {
            float cs = cpart[0][j] + cpart[1][j] + cpart[2][j] + cpart[3][j];
            float rs = rpart[0][j] + rpart[1][j] + rpart[2][j] + rpart[3][j];
            float g = (rs - cs) * ORD_SCALE;
            float m = 0.9f * g_mT[j] + 0.1f * g;
            float v = 0.999f * g_vT[j] + 0.001f * g * g;
            g_mT[j] = m; g_vT[j] = v;
            g_tau[par ^ 1][j] = tl[j] - 0.1f * (m / bc1) / (sqrtf(v / bc2) + 1e-8f);
        }
        return;
    }

    // ---- row u: fused prod + grad + Adam ----
    const int u = blockIdx.x;
    __shared__ float sl[NMAT];       // S_in[u,:]
    __shared__ float wl[NMAT];       // W[u,:]
    __shared__ float pp[4][256];     // partial products
    __shared__ float ap[4][256];     // partial grad accumulators
    if (tid < NMAT) sl[tid] = S_in[u * NMAT + tid];
    __syncthreads();

    // Phase A: P[u,j] = prod_k (1 - 2*B[j,k]*S[u,k]), chunked over k
    float p = 1.0f;
    if (j < NMAT) {
        #pragma unroll 4
        for (int k = c * CHW; k < c * CHW + CHW; ++k) {
            float b = g_Bt[k * NMAT + j];          // coalesced across j
            p *= (1.0f - 2.0f * b * sl[k]);        // sl[k]: LDS broadcast
        }
    }
    pp[c][j] = p;
    __syncthreads();
    if (c == 0 && j < NMAT) {
        float pr = pp[0][j] * pp[1][j] * pp[2][j] * pp[3][j];
        float t = (j == u) ? -1.0f : 1.0f;
        wl[j] = (pr - t) * pr;
    }
    __syncthreads();

    // Phase B: acc[j] = sum_w W[u,w] * B[w,j] / (1 - 2*B[w,j]*S[u,j]), chunked over w
    const float s = (j < NMAT) ? sl[j] : 0.f;
    float acc = 0.f;
    if (j < NMAT) {
        #pragma unroll 4
        for (int w = c * CHW; w < c * CHW + CHW; ++w) {
            float b = A[w * NFULL + 16 + j];       // coalesced across j
            float term = 1.0f - 2.0f * b * s;
            float r = __builtin_amdgcn_rcpf(term); // v_rcp_f32, ~1e-7 rel err
            acc += (term != 0.0f) ? wl[w] * b * r : 0.0f;
        }
    }
    ap[c][j] = acc;
    __syncthreads();

    if (c == 0 && j < NMAT) {
        float a4 = ap[0][j] + ap[1][j] + ap[2][j] + ap[3][j];
        float g_odd = -a4 * (1.0f / 240.0f);
        float d = tauin[u] - tauin[16 + j] + 0.1f;
        float r = fmaxf(d, 0.f);
        float gS  = g_odd + r * r * ORD_SCALE;
        float gGl = gS * s * (1.0f - s);           // sigmoid'
        const int idx = u * NMAT + j;
        float m = 0.9f * g_mG[idx] + 0.1f * gGl;
        float v = 0.999f * g_vG[idx] + 0.001f * gGl * gGl;
        g_mG[idx] = m; g_vG[idx] = v;
        float pnew = g_Gl[idx] - 0.1f * (m / bc1) / (sqrtf(v / bc2) + 1e-8f);
        g_Gl[idx] = pnew;
        g_S[par ^ 1][idx] = sigm(pnew);
    }
}

// Final loss: block u covers row u of L_odd and L_order, 4-way chunked products
__global__ __launch_bounds__(1024) void k_final(int par)
{
    __shared__ float sl[NMAT];
    __shared__ float pp[4][256];
    __shared__ float rodd[4], rord[4];
    const int u = blockIdx.x, tid = threadIdx.x;
    const int c = tid >> 8, j = tid & 255;
    const float* __restrict__ S   = g_S[par];
    const float* __restrict__ tau = g_tau[par];
    if (tid < NMAT) sl[tid] = S[u * NMAT + tid];
    __syncthreads();

    float p = 1.0f;
    if (j < NMAT) {
        #pragma unroll 4
        for (int k = c * CHW; k < c * CHW + CHW; ++k) {
            float b = g_Bt[k * NMAT + j];
            p *= (1.0f - 2.0f * b * sl[k]);
        }
    }
    pp[c][j] = p;
    __syncthreads();

    float odd = 0.f, ord = 0.f;
    if (c == 0 && j < NMAT) {
        float pr = pp[0][j] * pp[1][j] * pp[2][j] * pp[3][j];
        float t = (j == u) ? -1.0f : 1.0f;
        float r = pr - t;
        odd = r * r;
        float d = tau[u] - tau[16 + j] + 0.1f;
        float rr = fmaxf(d, 0.f);
        ord = sl[j] * rr * rr;
    }
    // reduce over the 4 waves of c==0 (others contribute 0)
    for (int off = 32; off > 0; off >>= 1) {
        odd += __shfl_down(odd, off);
        ord += __shfl_down(ord, off);
    }
    __syncthreads();
    int lane = tid & 63, wv = tid >> 6;
    if (lane == 0 && wv < 4) { rodd[wv] = odd; rord[wv] = ord; }
    __syncthreads();
    if (tid == 0) {
        float so = rodd[0] + rodd[1] + rodd[2] + rodd[3];
        float sr = rord[0] + rord[1] + rord[2] + rord[3];
        atomicAdd(&g_acc[0], so);
        atomicAdd(&g_acc[1], sr);
    }
}

__global__ void k_out(float* __restrict__ out)
{
    out[0] = g_acc[0] / 960.0f + g_acc[1] / 61440.0f;
}

extern "C" void kernel_launch(void* const* d_in, const int* in_sizes, int n_in,
                              void* d_out, int out_size, void* d_ws, size_t ws_size,
                              hipStream_t stream)
{
    const float* A    = (const float*)d_in[0];
    const float* Gl0  = (const float*)d_in[1];
    const float* tau0 = (const float*)d_in[2];
    float* out = (float*)d_out;

    k_init<<<(NG + 255) / 256, 256, 0, stream>>>(A, Gl0, tau0);

    for (int t = 0; t < ITERS; ++t) {
        int par = t & 1;
        double tt = (double)(t + 1);
        float bc1 = (float)(1.0 - pow((double)0.9f,   tt));
        float bc2 = (float)(1.0 - pow((double)0.999f, tt));
        k_iter<<<NMAT + 1, 1024, 0, stream>>>(A, par, bc1, bc2);
    }
    // after 30 iterations final params live in parity 0
    k_final<<<NMAT, 1024, 0, stream>>>(0);
    k_out<<<1, 1, 0, stream>>>(out);
}